// Round 13
// baseline (49.381 us; speedup 1.0000x reference)
//
#include <hip/hip_runtime.h>
#include <math.h>

#define TEMP 13.544f
#define TBL 2048

__device__ __forceinline__ double lut_f(double s, double a, double b) {
    double w = a * s - b;
    if (w > 35.0) return 18.420680743952367;  // -log(1e-8)
    double E = exp(w);
    return log((1.0 + E) / (1.0 + 1e-8 * (1.0 + E)));
}

// ---------------- setup: blocks [0,B) decode mask + zero sums; blocks [B,..) build LUT (V/D split) ----------------
__global__ __launch_bounds__(256) void setup_kernel(const void* __restrict__ mask_raw,
                                                    int B, int N,
                                                    int* __restrict__ msk,
                                                    int* __restrict__ nv,
                                                    double* __restrict__ sums,
                                                    const float* __restrict__ pa,
                                                    const float* __restrict__ pb,
                                                    float* __restrict__ lutV,
                                                    float* __restrict__ lutD) {
    int blk = blockIdx.x;
    int t = threadIdx.x;

    if (blk >= B) {
        int k = (blk - B) * 256 + t;
        if (k < TBL) {
            double a = (double)pa[0]; if (a < 1e-30) a = 1e-30;
            double b = (double)pb[0];
            double S = (40.0 + b) / a; if (!(S > 1e-30)) S = 1e-30;
            double h = S / (double)TBL;
            double x0 = (double)k * h;
            double v0 = lut_f(x0, a, b);
            double v1 = lut_f(x0 + h, a, b);
            double vm = lut_f(x0 + 0.5 * h, a, b);
            double dev = 0.5 * (v0 + v1) - vm;          // endpoint-interp error at midpoint
            // Chebyshev-shifted linear: halves the max interpolation error
            lutV[k] = (float)(v0 - 0.5 * dev);
            lutD[k] = (float)(v1 - v0);
        }
        return;
    }

    int b = blk;
    __shared__ int flags[2];
    __shared__ int cnt[4];
    if (t < 2) flags[t] = 0;
    __syncthreads();
    const unsigned int* mi = (const unsigned int*)mask_raw;
    int total = B * N;
    int scan = total < 256 ? total : 256;
    if (t < scan) {
        unsigned int v = mi[t];
        if (v == 0x3F800000u) atomicOr(&flags[0], 1);
        else if (v > 1u)      atomicOr(&flags[1], 1);
    }
    __syncthreads();
    int layout = flags[0] ? 2 : (flags[1] ? 1 : 0);  // 0=i32, 1=u8, 2=f32

    int c = 0;
    for (int j = t; j < N; j += 256) {
        int v;
        if (layout == 0)      v = (((const int*)mask_raw)[b * N + j] != 0);
        else if (layout == 1) v = (((const unsigned char*)mask_raw)[b * N + j] != 0);
        else                  v = (((const float*)mask_raw)[b * N + j] != 0.0f);
        msk[b * N + j] = v;
        c += v;
    }
    #pragma unroll
    for (int off = 32; off > 0; off >>= 1) c += __shfl_down(c, off, 64);
    int lane = t & 63, wid = t >> 6;
    if (lane == 0) cnt[wid] = c;
    __syncthreads();
    if (t == 0) {
        nv[b] = cnt[0] + cnt[1] + cnt[2] + cnt[3];
        sums[b * 2 + 0] = 0.0;
        sums[b * 2 + 1] = 0.0;
    }
}

// ---------------- tsm: 512 threads = 16x16 tile x 2 p-phases; dual-b32 LUT lerp; fused f64 stats ----------------
__global__ __launch_bounds__(512, 4) void tsm_kernel(const float* __restrict__ X,
                                                     const float* __restrict__ pa,
                                                     const float* __restrict__ pb,
                                                     const int* __restrict__ msk,
                                                     const int* __restrict__ nv,
                                                     const float* __restrict__ lutVg,
                                                     const float* __restrict__ lutDg,
                                                     float* __restrict__ tsm,
                                                     double* __restrict__ sums,
                                                     int N) {
    const int b = blockIdx.y;
    const int t = threadIdx.x;
    const int nt = N / 16;

    // decode linear upper-tri index -> (by, bx), by <= bx  (wave-uniform short loop)
    int k = blockIdx.x, by = 0;
    while (k >= nt - by) { k -= nt - by; by++; }
    const int bx = k + by;

    const int i0 = by * 16, j0 = bx * 16;
    const int nvb = nv[b];
    if (i0 >= nvb || j0 >= nvb) return;   // contiguous-prefix mask: tile dead

    __shared__ __align__(16) float tblV[TBL];
    __shared__ __align__(16) float tblD[TBL];
    __shared__ float red[256];
    __shared__ double wsum[4], wsum2[4];
    {
        ((float4*)tblV)[t] = ((const float4*)lutVg)[t];   // 512 thr x 16B = 2048 floats
        ((float4*)tblD)[t] = ((const float4*)lutDg)[t];
    }

    float aa = pa[0], bb = pb[0];
    double ad = (double)aa; if (ad < 1e-30) ad = 1e-30;
    double S = (40.0 + (double)bb) / ad; if (!(S > 1e-30)) S = 1e-30;
    const float r = sqrtf((float)((double)TBL / S));   // prescale so fi = (r*dx)^2

    const int ph = t >> 8;                 // which 8 p-components
    const int tl = t & 255;
    const int ti = tl >> 4, tj = tl & 15;
    const float* Xb = X + (size_t)b * N * 16;

    float xi[16], xj[8];
    {
        const float4* rowi = (const float4*)&Xb[(i0 + ti) * 16];
        const float4* rowj = (const float4*)&Xb[(j0 + tj) * 16 + ph * 8];
        #pragma unroll
        for (int kk = 0; kk < 4; kk++) {
            float4 vi = rowi[kk];
            xi[4 * kk + 0] = vi.x * r; xi[4 * kk + 1] = vi.y * r;
            xi[4 * kk + 2] = vi.z * r; xi[4 * kk + 3] = vi.w * r;
        }
        #pragma unroll
        for (int kk = 0; kk < 2; kk++) {
            float4 vj = rowj[kk];
            xj[4 * kk + 0] = vj.x * r; xj[4 * kk + 1] = vj.y * r;
            xj[4 * kk + 2] = vj.z * r; xj[4 * kk + 3] = vj.w * r;
        }
    }
    __syncthreads();   // tables visible

    float acc0 = 0.0f, acc1 = 0.0f, acc2 = 0.0f, acc3 = 0.0f;
    #pragma unroll
    for (int p = 0; p < 8; p++) {
        float xv = xj[p];
        #pragma unroll
        for (int h = 0; h < 2; h++) {
            float fr[8];
            int   ix[8];
            #pragma unroll
            for (int q = 0; q < 8; q++) {
                float d  = xi[h * 8 + q] - xv;
                float fi = fminf(d * d, (float)TBL - 0.01f);
                float ft = truncf(fi);
                fr[q] = fi - ft;
                ix[q] = (int)ft;
            }
            float vv[8], dd[8];
            #pragma unroll
            for (int q = 0; q < 8; q++) vv[q] = tblV[ix[q]];
            #pragma unroll
            for (int q = 0; q < 8; q++) dd[q] = tblD[ix[q]];
            acc0 += fmaf(fr[0], dd[0], vv[0]);
            acc1 += fmaf(fr[1], dd[1], vv[1]);
            acc2 += fmaf(fr[2], dd[2], vv[2]);
            acc3 += fmaf(fr[3], dd[3], vv[3]);
            acc0 += fmaf(fr[4], dd[4], vv[4]);
            acc1 += fmaf(fr[5], dd[5], vv[5]);
            acc2 += fmaf(fr[6], dd[6], vv[6]);
            acc3 += fmaf(fr[7], dd[7], vv[7]);
        }
    }
    float vp = (acc0 + acc1) + (acc2 + acc3);

    // cross-phase reduction: ph1 -> LDS, ph0 adds and finalizes
    if (ph == 1) red[tl] = vp;
    __syncthreads();

    double x = 0.0, x2 = 0.0;
    if (ph == 0) {
        float v = (vp + red[tl]) * (1.0f / 256.0f);
        const int i = i0 + ti, j = j0 + tj;
        tsm[((size_t)b * N + i) * N + j] = v;
        if (bx != by) tsm[((size_t)b * N + j) * N + i] = v;

        int m2 = msk[b * N + i] & msk[b * N + j];
        double wgt = (bx == by) ? 1.0 : 2.0;
        x  = m2 ? (double)v * wgt : 0.0;
        x2 = m2 ? (double)v * (double)v * wgt : 0.0;
        #pragma unroll
        for (int off = 32; off > 0; off >>= 1) {
            x  += __shfl_down(x,  off, 64);
            x2 += __shfl_down(x2, off, 64);
        }
        int lane = tl & 63, wid = tl >> 6;
        if (lane == 0) { wsum[wid] = x; wsum2[wid] = x2; }
    }
    __syncthreads();
    if (t == 0) {
        atomicAdd(&sums[b * 2 + 0], wsum[0] + wsum[1] + wsum[2] + wsum[3]);
        atomicAdd(&sums[b * 2 + 1], wsum2[0] + wsum2[1] + wsum2[2] + wsum2[3]);
    }
}

// ---------------- softmax per row ----------------
__global__ __launch_bounds__(256) void softmax_kernel(const float* __restrict__ tsm,
                                                      const int* __restrict__ msk,
                                                      const int* __restrict__ nv,
                                                      const double* __restrict__ sums,
                                                      float* __restrict__ out,
                                                      int N) {
    const int b = blockIdx.y;
    const int i = blockIdx.x;
    const int t = threadIdx.x;
    const float* row  = tsm + ((size_t)b * N + i) * N;
    float*       orow = out + ((size_t)b * N + i) * N;

    const int mi = msk[b * N + i];
    const int n1 = nv[b];
    if (!mi || n1 == 0) {
        for (int j = t; j < N; j += 256) orow[j] = 0.0f;
        return;
    }

    double ntot = (double)n1 * (double)n1;
    double S  = sums[b * 2 + 0];
    double S2 = sums[b * 2 + 1];
    double mean = S / ntot;
    double var  = (ntot > 1.5) ? (S2 - S * S / ntot) / (ntot - 1.0) : 1.0;
    if (var < 1e-30) var = 1e-30;
    float fmean = (float)mean;
    float inv   = (float)(1.0 / (sqrt(var) * (double)TEMP));

    float l[4];
    int   mj[4];
    int nch = (N + 255) / 256;
    float mx = -INFINITY;
    for (int c = 0; c < nch; c++) {
        int j = t + c * 256;
        mj[c] = msk[b * N + j];
        l[c]  = (fmean - row[j]) * inv;
        if (mj[c]) mx = fmaxf(mx, l[c]);
    }
    __shared__ float red[4];
    #pragma unroll
    for (int off = 32; off > 0; off >>= 1) mx = fmaxf(mx, __shfl_down(mx, off, 64));
    if ((t & 63) == 0) red[t >> 6] = mx;
    __syncthreads();
    mx = fmaxf(fmaxf(red[0], red[1]), fmaxf(red[2], red[3]));
    __syncthreads();

    float e[4];
    float sum = 0.0f;
    for (int c = 0; c < nch; c++) {
        e[c] = mj[c] ? __expf(l[c] - mx) : 0.0f;
        sum += e[c];
    }
    #pragma unroll
    for (int off = 32; off > 0; off >>= 1) sum += __shfl_down(sum, off, 64);
    if ((t & 63) == 0) red[t >> 6] = sum;
    __syncthreads();
    sum = red[0] + red[1] + red[2] + red[3];

    float rs = 1.0f / sum;
    for (int c = 0; c < nch; c++) {
        int j = t + c * 256;
        orow[j] = mj[c] ? e[c] * rs : 0.0f;
    }
}

extern "C" void kernel_launch(void* const* d_in, const int* in_sizes, int n_in,
                              void* d_out, int out_size, void* d_ws, size_t ws_size,
                              hipStream_t stream) {
    const float* X    = (const float*)d_in[0];
    const void*  mask = d_in[1];
    const float* pa   = (const float*)d_in[2];
    const float* pb   = (const float*)d_in[3];

    int BN = in_sizes[1];          // B*N
    int N  = out_size / BN;        // 512
    int B  = BN / N;               // 2

    float* out = (float*)d_out;
    char*  ws  = (char*)d_ws;

    // layout: lutV | lutD | tsm | sums | msk | nv
    float* lutV = (float*)ws;
    float* lutD = (float*)(ws + (size_t)TBL * sizeof(float));
    size_t lutBytes = (size_t)2 * TBL * sizeof(float);
    float* tsm = (float*)(ws + lutBytes);
    size_t tsmBytes = (size_t)B * N * N * sizeof(float);
    double* sums = (double*)(ws + lutBytes + tsmBytes);
    size_t sumsBytes = (size_t)B * 2 * sizeof(double);
    int* msk = (int*)(ws + lutBytes + tsmBytes + sumsBytes);
    size_t mskBytes = (size_t)B * N * sizeof(int);
    int* nv = (int*)(ws + lutBytes + tsmBytes + sumsBytes + mskBytes);

    setup_kernel<<<B + TBL / 256, 256, 0, stream>>>(mask, B, N, msk, nv, sums, pa, pb, lutV, lutD);

    int nt = N / 16;
    dim3 g1(nt * (nt + 1) / 2, B);
    tsm_kernel<<<g1, 512, 0, stream>>>(X, pa, pb, msk, nv, lutV, lutD, tsm, sums, N);

    dim3 g2(N, B);
    softmax_kernel<<<g2, 256, 0, stream>>>(tsm, msk, nv, sums, out, N);
}